// Round 5
// baseline (465.469 us; speedup 1.0000x reference)
//
#include <hip/hip_runtime.h>
#include <math.h>

#define IMSZ 28
#define PSZ  8
#define LAMF 0.001f
#define CSTRIDE 240      // cvbuf stride (225 used, padded)
#define SSTR 17          // sS row stride (bank-conflict-free)
#define MAXBLK 256
#define NST 225          // 15*15 coact entries

__device__ __forceinline__ float devload(const float* p) {
    return __hip_atomic_load(p, __ATOMIC_RELAXED, __HIP_MEMORY_SCOPE_AGENT);
}
__device__ __forceinline__ unsigned devloadu(const unsigned* p) {
    return __hip_atomic_load(p, __ATOMIC_RELAXED, __HIP_MEMORY_SCOPE_AGENT);
}
__device__ __forceinline__ void devstore(float* p, float v) {
    __hip_atomic_store(p, v, __ATOMIC_RELAXED, __HIP_MEMORY_SCOPE_AGENT);
}
__device__ __forceinline__ void devstoreu(unsigned* p, unsigned v) {
    __hip_atomic_store(p, v, __ATOMIC_RELAXED, __HIP_MEMORY_SCOPE_AGENT);
}

// Sum over the 8 contiguous lanes of a group, result in all 8 lanes.
// Stages: quad_perm [1,0,3,2] (xor1), quad_perm [2,3,0,1] (xor2), then
// row_half_mirror (lane i <- 7-i within each 8-lane half-row). After the
// two quad stages the value is quad-uniform, so mirror == xor4 bitwise.
// Pure VALU pipe; replaces 3 ds_swizzle per value.
__device__ __forceinline__ float dpp_sum8(float v) {
    int t;
    t = __builtin_amdgcn_update_dpp(0, __float_as_int(v), 0xB1, 0xF, 0xF, true);
    v += __int_as_float(t);
    t = __builtin_amdgcn_update_dpp(0, __float_as_int(v), 0x4E, 0xF, 0xF, true);
    v += __int_as_float(t);
    t = __builtin_amdgcn_update_dpp(0, __float_as_int(v), 0x141, 0xF, 0xF, true);
    v += __int_as_float(t);
    return v;
}

// One persistent kernel: all 5 steps fused. 256 blocks x 1024 threads
// (1 block/CU by capacity -> all resident, deadlock-free). 128 groups of
// 8 lanes x 2 samples = 256 samples/block. State in LDS, positions in regs.
//
// Per-step exchange (lesson of r2-r4): relaxed agent stores + flag polls
// (no RMW, no acquire-invalidate), single reducer block, and -- new this
// round -- TRANSPOSED slot layout slots[t][b] so the reducer's lanes read
// consecutive addresses (4 line-requests per wave instr instead of 64).
// The flag store happens right after the coact partial; control/gather/
// input-matvec for the next step execute inside the reduce shadow; only
// the recurrent FMAs wait on the ready word.
__global__ __launch_bounds__(1024, 4) void fused5(
    const float* __restrict__ x,
    const float* __restrict__ Wi, const float* __restrict__ bi,
    const float* __restrict__ gamma, const float* __restrict__ beta,
    const float* __restrict__ R, const float* __restrict__ rb,
    const float* __restrict__ mask,
    const float* __restrict__ Wc, const float* __restrict__ bc,
    const float* __restrict__ Wo, const float* __restrict__ bo,
    float* __restrict__ slots, float* __restrict__ cvbuf,
    unsigned* __restrict__ bar, unsigned* __restrict__ ready,
    float* __restrict__ out, float invB, int nblk)
{
    __shared__ float sWi[15 * 72];          // row stride 72
    __shared__ float sBi[16], sGa[16], sBe[16], sRb[16];
    __shared__ float sWc[32], sBc[2], sWo[160], sBo[16];
    __shared__ float sRm[226], sLm[226];    // R*mask, (LAM/B)*mask
    __shared__ float sReff[240];            // 225 live + zero pad (c==7 column)
    __shared__ float sCoQ[4][226];          // coact quarter partials
    __shared__ float sS[256 * SSTR];        // per-block state [sample][unit]

    const int tid = threadIdx.x;

    // ---- stage constants ONCE (disjoint thread ranges) ----
    for (int idx = tid; idx < 990; idx += 1024) {
        int u = idx / 66, k = idx - u * 66;
        sWi[u * 72 + k] = Wi[idx];
    }
    if (tid < 15) {
        sBi[tid] = bi[tid]; sGa[tid] = gamma[tid];
        sBe[tid] = beta[tid]; sRb[tid] = rb[tid];
    }
    if (tid >= 32 && tid < 62)  sWc[tid - 32] = Wc[tid - 32];
    if (tid >= 62 && tid < 64)  sBc[tid - 62] = bc[tid - 62];
    if (tid >= 96 && tid < 246) sWo[tid - 96] = Wo[tid - 96];
    if (tid >= 246 && tid < 256) sBo[tid - 246] = bo[tid - 246];
    if (tid >= 256 && tid < 481) {
        int t = tid - 256;
        float m = mask[t];
        sRm[t] = R[t] * m;
        sLm[t] = (LAMF * invB) * m;
    }
    if (tid >= 481 && tid < 496) sReff[tid - 256] = 0.0f;   // pad stays 0
    __syncthreads();

    const int g = tid >> 3;                  // group / sample slot (0..127)
    const int c = tid & 7;                   // lane handles patch COLUMN c
    const int b0 = blockIdx.x * 256 + g;
    const int b1 = b0 + 128;
    const float* img0 = x + (size_t)b0 * (IMSZ * IMSZ);
    const float* img1 = x + (size_t)b1 * (IMSZ * IMSZ);

    int pr0 = 10, pc0 = 10, pr1 = 10, pc1 = 10;
    float hA[15], hB[15];

    // ---- step 0 prologue: gather + input matvec (pos feature == 0 exactly) ----
    {
        float pA[8], pB[8];
        const float* q0 = img0 + (10 * IMSZ + 10) + c;
        const float* q1 = img1 + (10 * IMSZ + 10) + c;
#pragma unroll
        for (int r = 0; r < 8; ++r) { pA[r] = q0[r * IMSZ]; pB[r] = q1[r * IMSZ]; }
#pragma unroll
        for (int u = 0; u < 15; ++u) {
            const float* w = sWi + u * 72 + c;
            float a = 0.f, bq = 0.f;
#pragma unroll
            for (int r = 0; r < 8; ++r) {
                float wv = w[r * 8];
                a  = fmaf(pA[r], wv, a);
                bq = fmaf(pB[r], wv, bq);
            }
            if (c == 0) { a += sBi[u]; bq += sBi[u]; }   // fr=fc=0 -> exact
            hA[u] = a; hB[u] = bq;
        }
    }

    for (int s = 0; s < 5; ++s) {
        if (s > 0) {
            // ---- recurrent add (sReff built at end of prev iter) ----
            float sj0A = sS[g * SSTR + c];
            float sj0B = sS[(g + 128) * SSTR + c];
            float sj1A = (c < 7) ? sS[g * SSTR + 8 + c] : 0.f;
            float sj1B = (c < 7) ? sS[(g + 128) * SSTR + 8 + c] : 0.f;
#pragma unroll
            for (int u = 0; u < 15; ++u) {
                float w0 = sReff[u * 15 + c];
                float w1 = sReff[u * 15 + 8 + c];     // c==7 -> zero pad
                hA[u] = fmaf(sj0A, w0, hA[u]); hA[u] = fmaf(sj1A, w1, hA[u]);
                hB[u] = fmaf(sj0B, w0, hB[u]); hB[u] = fmaf(sj1B, w1, hB[u]);
            }
        }

        // ---- 8-lane DPP all-reduce, relu ----
#pragma unroll
        for (int u = 0; u < 15; ++u) {
            hA[u] = fmaxf(dpp_sum8(hA[u]), 0.0f);
            hB[u] = fmaxf(dpp_sum8(hB[u]), 0.0f);
        }

        // ---- LayerNorm, in place (redundant per lane) ----
        float muA = 0.f, muB = 0.f;
#pragma unroll
        for (int u = 0; u < 15; ++u) { muA += hA[u]; muB += hB[u]; }
        muA *= (1.0f / 15.0f); muB *= (1.0f / 15.0f);
        float vA = 0.f, vB = 0.f;
#pragma unroll
        for (int u = 0; u < 15; ++u) {
            float dA = hA[u] - muA; vA = fmaf(dA, dA, vA);
            float dB = hB[u] - muB; vB = fmaf(dB, dB, vB);
        }
        vA *= (1.0f / 15.0f); vB *= (1.0f / 15.0f);
        const float rsA = 1.0f / sqrtf(vA + 1e-5f);
        const float rsB = 1.0f / sqrtf(vB + 1e-5f);
#pragma unroll
        for (int u = 0; u < 15; ++u) {
            hA[u] = (hA[u] - muA) * rsA * sGa[u] + sBe[u];
            hB[u] = (hB[u] - muB) * rsB * sGa[u] + sBe[u];
        }

        if (s == 4) {
            // ---- logits, done ----
#pragma unroll
            for (int rep = 0; rep < 2; ++rep) {
                int o = rep * 8 + c;
                if (o < 10) {
                    float a0 = 0.f, a1 = 0.f;
#pragma unroll
                    for (int j = 0; j < 15; ++j) {
                        a0 = fmaf(hA[j], sWo[o * 15 + j], a0);
                        a1 = fmaf(hB[j], sWo[o * 15 + j], a1);
                    }
                    out[(size_t)b0 * 10 + o] = a0 + sBo[o];
                    out[(size_t)b1 * 10 + o] = a1 + sBo[o];
                }
            }
            break;
        }

        // ---- control head + position update (redundant per lane) ----
        {
            float c0A = 0.f, c1A = 0.f, c0B = 0.f, c1B = 0.f;
#pragma unroll
            for (int j = 0; j < 15; ++j) {
                c0A = fmaf(hA[j], sWc[j],      c0A);
                c1A = fmaf(hA[j], sWc[15 + j], c1A);
                c0B = fmaf(hB[j], sWc[j],      c0B);
                c1B = fmaf(hB[j], sWc[15 + j], c1B);
            }
            c0A = tanhf(c0A + sBc[0]); c1A = tanhf(c1A + sBc[1]);
            c0B = tanhf(c0B + sBc[0]); c1B = tanhf(c1B + sBc[1]);
            {
                float m0 = fabsf(c0A), m1 = fabsf(c1A);
                int rm, cm;
                if (m0 >= m1) { rm = (c0A > 0.f) - (c0A < 0.f); cm = 0; }
                else          { rm = 0; cm = (c1A > 0.f) - (c1A < 0.f); }
                pr0 = min(max(pr0 + rm, 0), IMSZ - PSZ);
                pc0 = min(max(pc0 + cm, 0), IMSZ - PSZ);
            }
            {
                float m0 = fabsf(c0B), m1 = fabsf(c1B);
                int rm, cm;
                if (m0 >= m1) { rm = (c0B > 0.f) - (c0B < 0.f); cm = 0; }
                else          { rm = 0; cm = (c1B > 0.f) - (c1B < 0.f); }
                pr1 = min(max(pr1 + rm, 0), IMSZ - PSZ);
                pc1 = min(max(pc1 + cm, 0), IMSZ - PSZ);
            }
        }

        // ---- gather for step s+1 (issue as early as possible) ----
        float pA[8], pB[8];
        {
            const float* q0 = img0 + pr0 * IMSZ + pc0 + c;
            const float* q1 = img1 + pr1 * IMSZ + pc1 + c;
#pragma unroll
            for (int r = 0; r < 8; ++r) { pA[r] = q0[r * IMSZ]; pB[r] = q1[r * IMSZ]; }
        }

        // ---- publish new state to LDS (compile-time reg indices only) ----
#pragma unroll
        for (int k = 0; k < 8; ++k) {
            if (c == k) {
                sS[g * SSTR + k]         = hA[k];
                sS[(g + 128) * SSTR + k] = hB[k];
                if (k < 7) {
                    sS[g * SSTR + 8 + k]         = hA[8 + k];
                    sS[(g + 128) * SSTR + 8 + k] = hB[8 + k];
                }
            }
        }
        __syncthreads();

        // ---- coact partials: 4 quarter-sets of 225 threads, 64 samples each ----
        {
            const int q = tid >> 8;          // 0..3
            const int t = tid & 255;
            if (t < NST) {
                int i = t / 15, j = t - i * 15;
                const int base = q * 64;
                float a0 = 0.f, a1 = 0.f, a2 = 0.f, a3 = 0.f;
#pragma unroll
                for (int bb = 0; bb < 64; bb += 4) {
                    a0 = fmaf(sS[(base + bb + 0) * SSTR + i], sS[(base + bb + 0) * SSTR + j], a0);
                    a1 = fmaf(sS[(base + bb + 1) * SSTR + i], sS[(base + bb + 1) * SSTR + j], a1);
                    a2 = fmaf(sS[(base + bb + 2) * SSTR + i], sS[(base + bb + 2) * SSTR + j], a2);
                    a3 = fmaf(sS[(base + bb + 3) * SSTR + i], sS[(base + bb + 3) * SSTR + j], a3);
                }
                sCoQ[q][t] = (a0 + a1) + (a2 + a3);
            }
        }
        __syncthreads();

        // ---- store this block's slot, TRANSPOSED: slots[t][b] ----
        if (tid < NST) {
            float v = (sCoQ[0][tid] + sCoQ[1][tid])
                    + (sCoQ[2][tid] + sCoQ[3][tid]);
            devstore(&slots[((size_t)s * NST + tid) * MAXBLK + blockIdx.x], v);
        }
        __syncthreads();   // drains vmcnt: slot stores complete at LLC

        if (tid == 0)
            devstoreu(&bar[s * MAXBLK + blockIdx.x], 1u);

        // ---- input matvec for step s+1 (inside the reduce shadow) ----
        {
            const float fr0 = ((float)pr0 / 20.0f) * 2.0f - 1.0f;
            const float fc0 = ((float)pc0 / 20.0f) * 2.0f - 1.0f;
            const float fr1 = ((float)pr1 / 20.0f) * 2.0f - 1.0f;
            const float fc1 = ((float)pc1 / 20.0f) * 2.0f - 1.0f;
#pragma unroll
            for (int u = 0; u < 15; ++u) {
                const float* w = sWi + u * 72 + c;
                float a = 0.f, bq = 0.f;
#pragma unroll
                for (int r = 0; r < 8; ++r) {
                    float wv = w[r * 8];
                    a  = fmaf(pA[r], wv, a);
                    bq = fmaf(pB[r], wv, bq);
                }
                if (c == 0) {
                    float wr = sWi[u * 72 + 64], wc = sWi[u * 72 + 65];
                    float bias = sBi[u] + sRb[u];
                    a  = fmaf(fr0, wr, a);  a  = fmaf(fc0, wc, a);  a  += bias;
                    bq = fmaf(fr1, wr, bq); bq = fmaf(fc1, wc, bq); bq += bias;
                }
                hA[u] = a; hB[u] = bq;
            }
        }

        // ---- exchange: reduce slots -> cvbuf -> sReff for step s+1 ----
        if (blockIdx.x == 0) {
            // wait for all block flags
            if (tid < 64) {
                const unsigned* bs = bar + s * MAXBLK;
                for (;;) {
                    unsigned f = 1u;
#pragma unroll
                    for (int k = 0; k < 4; ++k) {
                        int b = tid + k * 64;
                        unsigned v = (b < nblk) ? devloadu(&bs[b]) : 1u;
                        f &= v;
                    }
                    if (__all(f != 0)) break;
                    __builtin_amdgcn_s_sleep(2);
                }
            }
            __syncthreads();
            // 16-wave reduce: wave w owns t = w*15 .. w*15+14; lanes read
            // consecutive blocks -> coalesced line requests.
            {
                const int wid = tid >> 6, ln = tid & 63;
                for (int j = 0; j < 15; ++j) {
                    int t = wid * 15 + j;
                    if (t < NST) {
                        const float* p = slots + ((size_t)s * NST + t) * MAXBLK + ln;
                        float v = 0.f;
#pragma unroll
                        for (int k = 0; k < 4; ++k) {
                            int b = k * 64 + ln;
                            v += (b < nblk) ? devload(p + k * 64) : 0.f;
                        }
                        v += __shfl_xor(v, 1);  v += __shfl_xor(v, 2);
                        v += __shfl_xor(v, 4);  v += __shfl_xor(v, 8);
                        v += __shfl_xor(v, 16); v += __shfl_xor(v, 32);
                        if (ln == 0) devstore(&cvbuf[s * CSTRIDE + t], v);
                    }
                }
            }
            __syncthreads();             // drain cv stores
            if (tid == 0)
                devstoreu(&ready[s * 16], 1u);
            if (tid < NST) {
                float cv = devload(&cvbuf[s * CSTRIDE + tid]);
                sReff[tid] = sRm[tid] - sLm[tid] * cv;
            }
            __syncthreads();             // sReff ready
        } else {
            if (tid < 64) {
                while (devloadu(&ready[s * 16]) == 0u)
                    __builtin_amdgcn_s_sleep(8);
            }
            __syncthreads();
            if (tid < NST) {
                float cv = devload(&cvbuf[s * CSTRIDE + tid]);
                sReff[tid] = sRm[tid] - sLm[tid] * cv;
            }
            __syncthreads();             // sReff ready
        }
    }
}

extern "C" void kernel_launch(void* const* d_in, const int* in_sizes, int n_in,
                              void* d_out, int out_size, void* d_ws, size_t ws_size,
                              hipStream_t stream) {
    (void)n_in; (void)out_size; (void)ws_size;
    const float* x     = (const float*)d_in[0];
    const float* Wi    = (const float*)d_in[1];
    const float* bi    = (const float*)d_in[2];
    const float* gamma = (const float*)d_in[3];
    const float* beta  = (const float*)d_in[4];
    const float* R     = (const float*)d_in[5];
    const float* rb    = (const float*)d_in[6];
    const float* mask  = (const float*)d_in[7];
    const float* Wc    = (const float*)d_in[8];
    const float* bc    = (const float*)d_in[9];
    const float* Wo    = (const float*)d_in[10];
    const float* bo    = (const float*)d_in[11];
    float* out = (float*)d_out;

    const int B = in_sizes[0] / (IMSZ * IMSZ);
    const float invB = 1.0f / (float)B;
    int grid = B / 256;                      // 256 samples per block -> 256 blocks

    // workspace layout:
    //   bar:   4 * MAXBLK u32 (block flags)            [zeroed each launch]
    //   ready: 4 * 16 u32 (one word per line)          [zeroed each launch]
    //   cvbuf: 4 * CSTRIDE f32                         [written before read]
    //   slots: 4 * NST * MAXBLK f32 (TRANSPOSED [t][b])[written before read]
    unsigned* bar   = (unsigned*)d_ws;
    unsigned* ready = bar + 4 * MAXBLK;
    float* cvbuf    = (float*)(ready + 4 * 16);
    float* slots    = cvbuf + 4 * CSTRIDE;

    hipMemsetAsync(d_ws, 0, (size_t)(4 * MAXBLK + 4 * 16) * sizeof(unsigned), stream);

    fused5<<<grid, 1024, 0, stream>>>(
        x, Wi, bi, gamma, beta, R, rb, mask, Wc, bc, Wo, bo,
        slots, cvbuf, bar, ready, out, invB, grid);
}

// Round 6
// 406.559 us; speedup vs baseline: 1.1449x; 1.1449x over previous
//
#include <hip/hip_runtime.h>
#include <math.h>

#define IMSZ 28
#define PSZ  8
#define LAMF 0.001f
#define CSTRIDE 240      // floats per slot/partial row (225 used, padded)
#define SSTR 17          // sS row stride (bank-conflict-free)
#define MAXBLK 256
#define NST 225          // 15*15 coact entries

__device__ __forceinline__ float devload(const float* p) {
    return __hip_atomic_load(p, __ATOMIC_RELAXED, __HIP_MEMORY_SCOPE_AGENT);
}
__device__ __forceinline__ unsigned devloadu(const unsigned* p) {
    return __hip_atomic_load(p, __ATOMIC_RELAXED, __HIP_MEMORY_SCOPE_AGENT);
}
__device__ __forceinline__ void devstore(float* p, float v) {
    __hip_atomic_store(p, v, __ATOMIC_RELAXED, __HIP_MEMORY_SCOPE_AGENT);
}
__device__ __forceinline__ void devstoreu(unsigned* p, unsigned v) {
    __hip_atomic_store(p, v, __ATOMIC_RELAXED, __HIP_MEMORY_SCOPE_AGENT);
}

// Sum over the 8 contiguous lanes of a group, result in all 8 lanes.
// quad_perm xor1, quad_perm xor2, row_half_mirror (== xor4 once quad-uniform).
// Pure VALU pipe. Numerically proven in r5 (absmax unchanged).
__device__ __forceinline__ float dpp_sum8(float v) {
    int t;
    t = __builtin_amdgcn_update_dpp(0, __float_as_int(v), 0xB1, 0xF, 0xF, true);
    v += __int_as_float(t);
    t = __builtin_amdgcn_update_dpp(0, __float_as_int(v), 0x4E, 0xF, 0xF, true);
    v += __int_as_float(t);
    t = __builtin_amdgcn_update_dpp(0, __float_as_int(v), 0x141, 0xF, 0xF, true);
    v += __int_as_float(t);
    return v;
}

// One persistent kernel: 5 steps fused. 256 blocks x 1024 threads (1/CU by
// capacity -> all resident, deadlock-free). 128 groups x 8 lanes x 2 samples.
//
// Per-step exchange, redesigned around r3/r4/r5's joint lesson (the cost is
// the SERIAL LATENCY CHAIN, and every link must be line-coalesced and
// writer-disjoint):
//   all blocks : coact -> slot row slots[b][0..224] (15 disjoint lines)
//                -> drain -> flag bar[s][b]
//   16 reducers: poll 16 src flags (1 line) -> read 16 rows COALESCED
//                -> partial[r][0..224] -> drain -> pready[s][r]
//   all blocks : poll pready line (1 line) -> sum 16 partials COALESCED
//                -> sReff.  Input matvec for s+1 runs in the reduce shadow
//                (consumers before the poll; reducers after their reduce).
__global__ __launch_bounds__(1024, 4) void fused5(
    const float* __restrict__ x,
    const float* __restrict__ Wi, const float* __restrict__ bi,
    const float* __restrict__ gamma, const float* __restrict__ beta,
    const float* __restrict__ R, const float* __restrict__ rb,
    const float* __restrict__ mask,
    const float* __restrict__ Wc, const float* __restrict__ bc,
    const float* __restrict__ Wo, const float* __restrict__ bo,
    float* __restrict__ slots, float* __restrict__ partial,
    unsigned* __restrict__ bar, unsigned* __restrict__ pready,
    float* __restrict__ out, float invB, int nblk)
{
    __shared__ float sWi[15 * 72];          // row stride 72
    __shared__ float sBi[16], sGa[16], sBe[16], sRb[16];
    __shared__ float sWc[32], sBc[2], sWo[160], sBo[16];
    __shared__ float sRm[226], sLm[226];    // R*mask, (LAM/B)*mask
    __shared__ float sReff[240];            // 225 live + zero pad (c==7 column)
    __shared__ float sCoQ[4][226];          // coact quarter partials
    __shared__ float sS[256 * SSTR];        // per-block state [sample][unit]

    const int tid = threadIdx.x;
    const int nred = (nblk + 15) >> 4;      // reducer blocks (16 for nblk=256)

    // ---- stage constants ONCE (disjoint thread ranges) ----
    for (int idx = tid; idx < 990; idx += 1024) {
        int u = idx / 66, k = idx - u * 66;
        sWi[u * 72 + k] = Wi[idx];
    }
    if (tid < 15) {
        sBi[tid] = bi[tid]; sGa[tid] = gamma[tid];
        sBe[tid] = beta[tid]; sRb[tid] = rb[tid];
    }
    if (tid >= 32 && tid < 62)  sWc[tid - 32] = Wc[tid - 32];
    if (tid >= 62 && tid < 64)  sBc[tid - 62] = bc[tid - 62];
    if (tid >= 96 && tid < 246) sWo[tid - 96] = Wo[tid - 96];
    if (tid >= 246 && tid < 256) sBo[tid - 246] = bo[tid - 246];
    if (tid >= 256 && tid < 481) {
        int t = tid - 256;
        float m = mask[t];
        sRm[t] = R[t] * m;
        sLm[t] = (LAMF * invB) * m;
    }
    if (tid >= 481 && tid < 496) sReff[tid - 256] = 0.0f;   // pad stays 0
    __syncthreads();

    const int g = tid >> 3;                  // group / sample slot (0..127)
    const int c = tid & 7;                   // lane handles patch COLUMN c
    const int b0 = blockIdx.x * 256 + g;
    const int b1 = b0 + 128;
    const bool isRed = (blockIdx.x < (unsigned)nred);
    const float* img0 = x + (size_t)b0 * (IMSZ * IMSZ);
    const float* img1 = x + (size_t)b1 * (IMSZ * IMSZ);

    int pr0 = 10, pc0 = 10, pr1 = 10, pc1 = 10;
    float hA[15], hB[15];

    // ---- step 0 prologue: gather + input matvec (pos feature == 0 exactly) ----
    {
        float pA[8], pB[8];
        const float* q0 = img0 + (10 * IMSZ + 10) + c;
        const float* q1 = img1 + (10 * IMSZ + 10) + c;
#pragma unroll
        for (int r = 0; r < 8; ++r) { pA[r] = q0[r * IMSZ]; pB[r] = q1[r * IMSZ]; }
#pragma unroll
        for (int u = 0; u < 15; ++u) {
            const float* w = sWi + u * 72 + c;
            float a = 0.f, bq = 0.f;
#pragma unroll
            for (int r = 0; r < 8; ++r) {
                float wv = w[r * 8];
                a  = fmaf(pA[r], wv, a);
                bq = fmaf(pB[r], wv, bq);
            }
            if (c == 0) { a += sBi[u]; bq += sBi[u]; }   // fr=fc=0 -> exact
            hA[u] = a; hB[u] = bq;
        }
    }

    for (int s = 0; s < 5; ++s) {
        if (s > 0) {
            // ---- recurrent add (sReff built at end of prev iter) ----
            float sj0A = sS[g * SSTR + c];
            float sj0B = sS[(g + 128) * SSTR + c];
            float sj1A = (c < 7) ? sS[g * SSTR + 8 + c] : 0.f;
            float sj1B = (c < 7) ? sS[(g + 128) * SSTR + 8 + c] : 0.f;
#pragma unroll
            for (int u = 0; u < 15; ++u) {
                float w0 = sReff[u * 15 + c];
                float w1 = sReff[u * 15 + 8 + c];     // c==7 -> zero pad
                hA[u] = fmaf(sj0A, w0, hA[u]); hA[u] = fmaf(sj1A, w1, hA[u]);
                hB[u] = fmaf(sj0B, w0, hB[u]); hB[u] = fmaf(sj1B, w1, hB[u]);
            }
        }

        // ---- 8-lane DPP all-reduce, relu ----
#pragma unroll
        for (int u = 0; u < 15; ++u) {
            hA[u] = fmaxf(dpp_sum8(hA[u]), 0.0f);
            hB[u] = fmaxf(dpp_sum8(hB[u]), 0.0f);
        }

        // ---- LayerNorm, in place (redundant per lane) ----
        float muA = 0.f, muB = 0.f;
#pragma unroll
        for (int u = 0; u < 15; ++u) { muA += hA[u]; muB += hB[u]; }
        muA *= (1.0f / 15.0f); muB *= (1.0f / 15.0f);
        float vA = 0.f, vB = 0.f;
#pragma unroll
        for (int u = 0; u < 15; ++u) {
            float dA = hA[u] - muA; vA = fmaf(dA, dA, vA);
            float dB = hB[u] - muB; vB = fmaf(dB, dB, vB);
        }
        vA *= (1.0f / 15.0f); vB *= (1.0f / 15.0f);
        const float rsA = 1.0f / sqrtf(vA + 1e-5f);
        const float rsB = 1.0f / sqrtf(vB + 1e-5f);
#pragma unroll
        for (int u = 0; u < 15; ++u) {
            hA[u] = (hA[u] - muA) * rsA * sGa[u] + sBe[u];
            hB[u] = (hB[u] - muB) * rsB * sGa[u] + sBe[u];
        }

        if (s == 4) {
            // ---- logits, done ----
#pragma unroll
            for (int rep = 0; rep < 2; ++rep) {
                int o = rep * 8 + c;
                if (o < 10) {
                    float a0 = 0.f, a1 = 0.f;
#pragma unroll
                    for (int j = 0; j < 15; ++j) {
                        a0 = fmaf(hA[j], sWo[o * 15 + j], a0);
                        a1 = fmaf(hB[j], sWo[o * 15 + j], a1);
                    }
                    out[(size_t)b0 * 10 + o] = a0 + sBo[o];
                    out[(size_t)b1 * 10 + o] = a1 + sBo[o];
                }
            }
            break;
        }

        // ---- control head + position update (redundant per lane) ----
        {
            float c0A = 0.f, c1A = 0.f, c0B = 0.f, c1B = 0.f;
#pragma unroll
            for (int j = 0; j < 15; ++j) {
                c0A = fmaf(hA[j], sWc[j],      c0A);
                c1A = fmaf(hA[j], sWc[15 + j], c1A);
                c0B = fmaf(hB[j], sWc[j],      c0B);
                c1B = fmaf(hB[j], sWc[15 + j], c1B);
            }
            c0A = tanhf(c0A + sBc[0]); c1A = tanhf(c1A + sBc[1]);
            c0B = tanhf(c0B + sBc[0]); c1B = tanhf(c1B + sBc[1]);
            {
                float m0 = fabsf(c0A), m1 = fabsf(c1A);
                int rm, cm;
                if (m0 >= m1) { rm = (c0A > 0.f) - (c0A < 0.f); cm = 0; }
                else          { rm = 0; cm = (c1A > 0.f) - (c1A < 0.f); }
                pr0 = min(max(pr0 + rm, 0), IMSZ - PSZ);
                pc0 = min(max(pc0 + cm, 0), IMSZ - PSZ);
            }
            {
                float m0 = fabsf(c0B), m1 = fabsf(c1B);
                int rm, cm;
                if (m0 >= m1) { rm = (c0B > 0.f) - (c0B < 0.f); cm = 0; }
                else          { rm = 0; cm = (c1B > 0.f) - (c1B < 0.f); }
                pr1 = min(max(pr1 + rm, 0), IMSZ - PSZ);
                pc1 = min(max(pc1 + cm, 0), IMSZ - PSZ);
            }
        }

        // ---- gather for step s+1 (issue early; data lands in VGPRs) ----
        float pA[8], pB[8];
        {
            const float* q0 = img0 + pr0 * IMSZ + pc0 + c;
            const float* q1 = img1 + pr1 * IMSZ + pc1 + c;
#pragma unroll
            for (int r = 0; r < 8; ++r) { pA[r] = q0[r * IMSZ]; pB[r] = q1[r * IMSZ]; }
        }

        // ---- publish new state to LDS (compile-time reg indices only) ----
#pragma unroll
        for (int k = 0; k < 8; ++k) {
            if (c == k) {
                sS[g * SSTR + k]         = hA[k];
                sS[(g + 128) * SSTR + k] = hB[k];
                if (k < 7) {
                    sS[g * SSTR + 8 + k]         = hA[8 + k];
                    sS[(g + 128) * SSTR + 8 + k] = hB[8 + k];
                }
            }
        }
        __syncthreads();

        // ---- coact partials: 4 quarter-sets of 225 threads, 64 samples each ----
        {
            const int q = tid >> 8;          // 0..3
            const int t = tid & 255;
            if (t < NST) {
                int i = t / 15, j = t - i * 15;
                const int base = q * 64;
                float a0 = 0.f, a1 = 0.f, a2 = 0.f, a3 = 0.f;
#pragma unroll
                for (int bb = 0; bb < 64; bb += 4) {
                    a0 = fmaf(sS[(base + bb + 0) * SSTR + i], sS[(base + bb + 0) * SSTR + j], a0);
                    a1 = fmaf(sS[(base + bb + 1) * SSTR + i], sS[(base + bb + 1) * SSTR + j], a1);
                    a2 = fmaf(sS[(base + bb + 2) * SSTR + i], sS[(base + bb + 2) * SSTR + j], a2);
                    a3 = fmaf(sS[(base + bb + 3) * SSTR + i], sS[(base + bb + 3) * SSTR + j], a3);
                }
                sCoQ[q][t] = (a0 + a1) + (a2 + a3);
            }
        }
        __syncthreads();

        // ---- slot row store: 225 CONSECUTIVE floats (15 disjoint lines) ----
        if (tid < NST) {
            float v = (sCoQ[0][tid] + sCoQ[1][tid])
                    + (sCoQ[2][tid] + sCoQ[3][tid]);
            devstore(&slots[((size_t)s * MAXBLK + blockIdx.x) * CSTRIDE + tid], v);
        }
        __syncthreads();   // drains vmcnt: slot stores complete at LLC

        if (tid == 0)
            devstoreu(&bar[s * MAXBLK + blockIdx.x], 1u);

        if (isRed) {
            // ---- reducer r: poll its 16 source flags (one line) ----
            const int r = blockIdx.x;
            if (tid < 256) {                 // waves 0-3 poll independently
                const unsigned* bs = bar + s * MAXBLK + r * 16;
                const int lane = tid & 63;
                for (;;) {
                    unsigned v = 1u;
                    if (lane < 16)
                        v = (r * 16 + lane < nblk) ? devloadu(&bs[lane]) : 1u;
                    if (__all(v != 0)) break;
                    __builtin_amdgcn_s_sleep(1);
                }
                // ---- read 16 slot rows, lane-coalesced, sum ----
                if (tid < NST) {
                    const float* sp = slots
                        + ((size_t)s * MAXBLK + r * 16) * CSTRIDE + tid;
                    float a0 = 0.f, a1 = 0.f, a2 = 0.f, a3 = 0.f;
#pragma unroll
                    for (int k = 0; k < 16; k += 4) {
                        a0 += (r * 16 + k + 0 < nblk) ? devload(sp + (size_t)(k + 0) * CSTRIDE) : 0.f;
                        a1 += (r * 16 + k + 1 < nblk) ? devload(sp + (size_t)(k + 1) * CSTRIDE) : 0.f;
                        a2 += (r * 16 + k + 2 < nblk) ? devload(sp + (size_t)(k + 2) * CSTRIDE) : 0.f;
                        a3 += (r * 16 + k + 3 < nblk) ? devload(sp + (size_t)(k + 3) * CSTRIDE) : 0.f;
                    }
                    devstore(&partial[((size_t)s * 16 + r) * CSTRIDE + tid],
                             (a0 + a1) + (a2 + a3));
                }
            }
            __syncthreads();                 // drain partial stores (all waves)
            if (tid == 0)
                devstoreu(&pready[s * 16 + r], 1u);
        }

        // ---- input matvec for step s+1 (reduce shadow for consumers;
        //      after-reduce for reducers) ----
        {
            const float fr0 = ((float)pr0 / 20.0f) * 2.0f - 1.0f;
            const float fc0 = ((float)pc0 / 20.0f) * 2.0f - 1.0f;
            const float fr1 = ((float)pr1 / 20.0f) * 2.0f - 1.0f;
            const float fc1 = ((float)pc1 / 20.0f) * 2.0f - 1.0f;
#pragma unroll
            for (int u = 0; u < 15; ++u) {
                const float* w = sWi + u * 72 + c;
                float a = 0.f, bq = 0.f;
#pragma unroll
                for (int r = 0; r < 8; ++r) {
                    float wv = w[r * 8];
                    a  = fmaf(pA[r], wv, a);
                    bq = fmaf(pB[r], wv, bq);
                }
                if (c == 0) {
                    float wr = sWi[u * 72 + 64], wc = sWi[u * 72 + 65];
                    float bias = sBi[u] + sRb[u];
                    a  = fmaf(fr0, wr, a);  a  = fmaf(fc0, wc, a);  a  += bias;
                    bq = fmaf(fr1, wr, bq); bq = fmaf(fc1, wc, bq); bq += bias;
                }
                hA[u] = a; hB[u] = bq;
            }
        }

        // ---- all blocks: poll pready line, sum 16 partials, build sReff ----
        if (tid < 256) {                     // waves 0-3 only
            const unsigned* pr = pready + s * 16;
            const int lane = tid & 63;
            for (;;) {
                unsigned v = 1u;
                if (lane < 16)
                    v = (lane < nred) ? devloadu(&pr[lane]) : 1u;
                if (__all(v != 0)) break;
                __builtin_amdgcn_s_sleep(1);
            }
            if (tid < NST) {
                const float* pp = partial + (size_t)s * 16 * CSTRIDE + tid;
                float a0 = 0.f, a1 = 0.f, a2 = 0.f, a3 = 0.f;
#pragma unroll
                for (int k = 0; k < 16; k += 4) {
                    a0 += (k + 0 < nred) ? devload(pp + (size_t)(k + 0) * CSTRIDE) : 0.f;
                    a1 += (k + 1 < nred) ? devload(pp + (size_t)(k + 1) * CSTRIDE) : 0.f;
                    a2 += (k + 2 < nred) ? devload(pp + (size_t)(k + 2) * CSTRIDE) : 0.f;
                    a3 += (k + 3 < nred) ? devload(pp + (size_t)(k + 3) * CSTRIDE) : 0.f;
                }
                float cv = (a0 + a1) + (a2 + a3);
                sReff[tid] = sRm[tid] - sLm[tid] * cv;
            }
        }
        __syncthreads();                     // sReff visible to all waves
    }
}

extern "C" void kernel_launch(void* const* d_in, const int* in_sizes, int n_in,
                              void* d_out, int out_size, void* d_ws, size_t ws_size,
                              hipStream_t stream) {
    (void)n_in; (void)out_size; (void)ws_size;
    const float* x     = (const float*)d_in[0];
    const float* Wi    = (const float*)d_in[1];
    const float* bi    = (const float*)d_in[2];
    const float* gamma = (const float*)d_in[3];
    const float* beta  = (const float*)d_in[4];
    const float* R     = (const float*)d_in[5];
    const float* rb    = (const float*)d_in[6];
    const float* mask  = (const float*)d_in[7];
    const float* Wc    = (const float*)d_in[8];
    const float* bc    = (const float*)d_in[9];
    const float* Wo    = (const float*)d_in[10];
    const float* bo    = (const float*)d_in[11];
    float* out = (float*)d_out;

    const int B = in_sizes[0] / (IMSZ * IMSZ);
    const float invB = 1.0f / (float)B;
    int grid = B / 256;                      // 256 samples per block -> 256 blocks

    // workspace layout:
    //   bar:     4 * MAXBLK u32 (block flags)               [zeroed]
    //   pready:  4 * 16 u32 (one line per step)             [zeroed]
    //   partial: 4 * 16 * CSTRIDE f32                       [written before read]
    //   slots:   4 * MAXBLK * CSTRIDE f32 (row per block)   [written before read]
    unsigned* bar    = (unsigned*)d_ws;
    unsigned* pready = bar + 4 * MAXBLK;
    float* partial   = (float*)(pready + 4 * 16);
    float* slots     = partial + (size_t)4 * 16 * CSTRIDE;

    hipMemsetAsync(d_ws, 0, (size_t)(4 * MAXBLK + 4 * 16) * sizeof(unsigned), stream);

    fused5<<<grid, 1024, 0, stream>>>(
        x, Wi, bi, gamma, beta, R, rb, mask, Wc, bc, Wo, bo,
        slots, partial, bar, pready, out, invB, grid);
}